// Round 6
// baseline (266.575 us; speedup 1.0000x reference)
//
#include <hip/hip_runtime.h>
#include <math.h>

#define Ss 1024
#define Dd 1024
#define Hh 16
#define Kk 64

typedef __bf16 bf16x8 __attribute__((ext_vector_type(8)));
typedef __bf16 bf16x4 __attribute__((ext_vector_type(4)));
typedef float  f32x4  __attribute__((ext_vector_type(4)));

#define MFMA16(a, b, c) __builtin_amdgcn_mfma_f32_16x16x32_bf16(a, b, c, 0, 0, 0)

// ws element offsets (bf16 units)
#define XB_E   8388608u
#define WT_E   3145728u
#define WOT_E  1048576u
#define QKV_E  8388608u

// Q scale: (1/8) * log2(e) so attn can use raw v_exp_f32 (2^x).
#define QSC 0.18033688011112042f

// v_exp_f32 is natively 2^x; log2(e) is folded into the Q scale in gemm.
__device__ __forceinline__ float exp2_hw(float x) {
    float r; asm("v_exp_f32 %0, %1" : "=v"(r) : "v"(x)); return r;
}

// global -> LDS DMA, 16B per lane. LDS dest: wave-uniform base + lane*16.
typedef __attribute__((address_space(1))) const void gas_void;
typedef __attribute__((address_space(3))) void las_void;
__device__ __forceinline__ void gll16(const __bf16* g, char* l) {
    __builtin_amdgcn_global_load_lds((gas_void*)g, (las_void*)l, 16, 0, 0);
}

// ---------------------------------------------------------------------------
// prep: z<4 -> transpose+cast weight matrix z; z==4 -> cast x to bf16
// ---------------------------------------------------------------------------
__global__ __launch_bounds__(256) void prep(
    const float* __restrict__ x,
    const float* __restrict__ Wq, const float* __restrict__ Wk,
    const float* __restrict__ Wv, const float* __restrict__ Wo,
    __bf16* __restrict__ xb, __bf16* __restrict__ WT, __bf16* __restrict__ WoT)
{
    __shared__ float tile[64][65];
    const int z = blockIdx.z;
    const int t = threadIdx.x;

    if (z == 4) {   // x cast: 256 blocks, 32 rows x 1024 cols each
        size_t blk = blockIdx.y * 16 + blockIdx.x;
        const float4* src = (const float4*)(x + blk * 32768);
        bf16x4* dst = (bf16x4*)(((__bf16*)xb) + blk * 32768);
        #pragma unroll
        for (int u = 0; u < 32; ++u) {
            float4 v = src[u * 256 + t];
            dst[u * 256 + t] =
                (bf16x4){(__bf16)v.x, (__bf16)v.y, (__bf16)v.z, (__bf16)v.w};
        }
        return;
    }

    const float* src = (z == 0) ? Wq : (z == 1) ? Wk : (z == 2) ? Wv : Wo;
    __bf16* dst = (z < 3) ? (WT + (size_t)z * 1048576) : WoT;

    int r0 = blockIdx.y * 64, c0 = blockIdx.x * 64;
    int rr = t >> 2, cg = (t & 3) * 16;

    #pragma unroll
    for (int u = 0; u < 4; ++u) {
        float4 v = *(const float4*)(src + (size_t)(r0 + rr) * 1024 + c0 + cg + u * 4);
        tile[rr][cg + u * 4 + 0] = v.x;
        tile[rr][cg + u * 4 + 1] = v.y;
        tile[rr][cg + u * 4 + 2] = v.z;
        tile[rr][cg + u * 4 + 3] = v.w;
    }
    __syncthreads();
    bf16x8 o0, o1;
    #pragma unroll
    for (int jj = 0; jj < 8; ++jj) o0[jj] = (__bf16)tile[cg + jj][rr];
    #pragma unroll
    for (int jj = 0; jj < 8; ++jj) o1[jj] = (__bf16)tile[cg + 8 + jj][rr];
    __bf16* dp = dst + (size_t)(c0 + rr) * 1024 + r0 + cg;
    *(bf16x8*)dp = o0;
    *(bf16x8*)(dp + 8) = o1;
}

// ---------------------------------------------------------------------------
// bf16 MFMA GEMM, C = A(MxK) * Bt(NxK)^T.
// FILL-BANDWIDTH MODEL (calibrated R2-R5): time = max-per-CU staged bytes /
// ~27 GB/s/CU. Levers: fill-per-FLOP (tile area) + exact grid packing.
//  - mode 0 (QKV): BM=256, BN=384 -> grid (8,32)=256 blocks = 1/CU, 1 round.
//    Fill 1.25 MB/CU (vs 2.0 R5). LDS = 2*(32+48)KB = 163840 B exactly
//    (full pool; 147456 proven launchable in R4).
//  - mode 1 (out):  BM=256, BN=128 -> grid (8,32)=256 = 1/CU (fixes R5's
//    half-idle 128-block out-gemm). Fill 768 KB/CU.
// 8 waves (2M x 4N), per-wave 128 x BN/4. acc[8][NJ] (NJ=BN/64) lives in the
// unified VGPR/AGPR file; A/B fragments are (re)loaded per quadrant phase to
// keep live VGPRs under the 256/thread cap at 2 waves/SIMD.
// T2 XOR swizzle (linear LDS dest + inverse-swizzled global src + swizzled
// ds_read) keeps bank conflicts at 0. XCD row-chunk swizzle for A-panel L2
// reuse. 2-slot ping-pong, vmcnt(0)+barrier per tile (schedule variants
// measured null R2-R4 -- fill-bound).
// ---------------------------------------------------------------------------
template <int BN>
__global__ __launch_bounds__(512) void gemm_bt(
    const __bf16* __restrict__ A, const __bf16* __restrict__ Bt, int mode,
    __bf16* __restrict__ qb, __bf16* __restrict__ kb, __bf16* __restrict__ vb,
    const float* __restrict__ bq, const float* __restrict__ bk,
    const float* __restrict__ bv,
    float* __restrict__ outf, const float* __restrict__ bo)
{
    constexpr int NJ  = BN / 64;     // N fragments per wave (6 or 2)
    constexpr int NJH = NJ / 2;      // per phase-half
    constexpr int WN  = BN / 4;      // per-wave N span

    __shared__ __align__(16) __bf16 As[2][256][64];
    __shared__ __align__(16) __bf16 Bs[2][BN][64];

    const int t = threadIdx.x;
    const int wave = t >> 6, lane = t & 63;
    const int quad = lane >> 4, l16 = lane & 15;
    const int wm = wave >> 2, wn = wave & 3;          // 2M x 4N waves

    // Bijective XCD swizzle (nwg=256, cpx=32): each XCD owns 4 consecutive
    // M-rows x all N-cols -> A panels L2-resident per XCD.
    int g = blockIdx.y * gridDim.x + blockIdx.x;
    g = (g & 7) * 32 + (g >> 3);
    const int bx = g % gridDim.x, by = g / gridDim.x;
    const int m0 = by * 256, n0 = bx * BN;

    // Staging: thread t -> row (chunk*64 + t>>3), 16B piece (t&7).
    // Global col pre-swizzled so linear LDS (row, cb) holds global
    // (row, cb ^ ((row&7)<<4)).
    const int srow = t >> 3;
    const int scol = (((t & 7) ^ (srow & 7)) * 8);
    const __bf16* pa = A  + (size_t)(m0 + srow) * 1024 + scol;
    const __bf16* pb = Bt + (size_t)(n0 + srow) * 1024 + scol;
    char* lA = (char*)(&As[0][0][0]) + t * 16;
    char* lB = (char*)(&Bs[0][0][0]) + t * 16;

#define STAGE(slot, k0) do {                                                  \
        _Pragma("unroll")                                                     \
        for (int g_ = 0; g_ < 4; ++g_)                                        \
            gll16(pa + (k0) + g_ * 65536, lA + (slot) * 32768 + g_ * 8192);   \
        _Pragma("unroll")                                                     \
        for (int g_ = 0; g_ < BN / 64; ++g_)                                  \
            gll16(pb + (k0) + g_ * 65536, lB + (slot) * (BN * 128) + g_ * 8192); \
    } while (0)

    STAGE(0, 0);

    f32x4 acc[8][NJ];
    #pragma unroll
    for (int i = 0; i < 8; ++i)
        #pragma unroll
        for (int j = 0; j < NJ; ++j) acc[i][j] = (f32x4){0.f, 0.f, 0.f, 0.f};

    const int swz = (l16 & 7) << 4;   // read-side XOR (row&7 == l16&7)

    for (int it = 0; it < 16; ++it) {
        const int s = it & 1;
        // Tile it's DMAs complete per-wave; barrier -> visible to all waves,
        // and all waves' reads of slot s^1 (tile it-1) are done.
        asm volatile("s_waitcnt vmcnt(0)" ::: "memory");
        __builtin_amdgcn_s_barrier();
        if (it < 15) STAGE(s ^ 1, (it + 1) * 64);  // in flight across compute

        const char* baseA = (const char*)&As[s][0][0];
        const char* baseB = (const char*)&Bs[s][0][0];

        #pragma unroll
        for (int mh = 0; mh < 2; ++mh) {
            bf16x8 afr[4][2];
            #pragma unroll
            for (int mi = 0; mi < 4; ++mi) {
                int rowa = (wm * 128 + (mh * 4 + mi) * 16 + l16) * 128;
                afr[mi][0] = *(const bf16x8*)(baseA + rowa + ((quad * 16) ^ swz));
                afr[mi][1] = *(const bf16x8*)(baseA + rowa + ((64 + quad * 16) ^ swz));
            }
            #pragma unroll
            for (int nh = 0; nh < 2; ++nh) {
                bf16x8 bfr[NJH][2];
                #pragma unroll
                for (int nj = 0; nj < NJH; ++nj) {
                    int rowb = (wn * WN + (nh * NJH + nj) * 16 + l16) * 128;
                    bfr[nj][0] = *(const bf16x8*)(baseB + rowb + ((quad * 16) ^ swz));
                    bfr[nj][1] = *(const bf16x8*)(baseB + rowb + ((64 + quad * 16) ^ swz));
                }
                __builtin_amdgcn_s_setprio(1);
                #pragma unroll
                for (int mi = 0; mi < 4; ++mi)
                    #pragma unroll
                    for (int nj = 0; nj < NJH; ++nj)
                        acc[mh * 4 + mi][nh * NJH + nj] =
                            MFMA16(afr[mi][1], bfr[nj][1],
                            MFMA16(afr[mi][0], bfr[nj][0],
                                   acc[mh * 4 + mi][nh * NJH + nj]));
                __builtin_amdgcn_s_setprio(0);
            }
            if (mh == 0) __builtin_amdgcn_s_barrier();   // rhythm
        }
    }
#undef STAGE

    if (mode == 0) {
        #pragma unroll
        for (int mi = 0; mi < 8; ++mi) {
            int row = m0 + wm * 128 + mi * 16 + quad * 4;
            int b = row >> 10, sx = row & 1023;
            #pragma unroll
            for (int nj = 0; nj < NJ; ++nj) {
                // 16-col fragments are 16-aligned; 1024-boundaries are too,
                // so z (which of Q/K/V this fragment hits) is per-fragment
                // uniform even though BN=384 tiles straddle boundaries.
                int c16 = n0 + wn * WN + nj * 16;
                int z = c16 >> 10;
                int n1 = (c16 + l16) & 1023;
                int h = n1 >> 6, ch = n1 & 63;
                if (z == 0) {
                    float bia = bq[n1];
                    __bf16* dst = qb + ((size_t)(b * Hh + h) * Ss + sx) * Kk + ch;
                    #pragma unroll
                    for (int r = 0; r < 4; ++r)
                        dst[(size_t)r * Kk] = (__bf16)((acc[mi][nj][r] + bia) * QSC);
                } else if (z == 1) {
                    float bia = bk[n1];
                    __bf16* dst = kb + ((size_t)(b * Hh + h) * Ss + sx) * Kk + ch;
                    #pragma unroll
                    for (int r = 0; r < 4; ++r)
                        dst[(size_t)r * Kk] = (__bf16)(acc[mi][nj][r] + bia);
                } else {
                    float bia = bv[n1];
                    bf16x4 o;
                    #pragma unroll
                    for (int r = 0; r < 4; ++r) o[r] = (__bf16)(acc[mi][nj][r] + bia);
                    *(bf16x4*)(vb + ((size_t)(b * Hh + h) * Kk + ch) * Ss + sx) = o;
                }
            }
        }
    } else {
        #pragma unroll
        for (int mi = 0; mi < 8; ++mi) {
            int row = m0 + wm * 128 + mi * 16 + quad * 4;
            #pragma unroll
            for (int nj = 0; nj < NJ; ++nj) {
                int n = n0 + wn * WN + nj * 16 + l16;
                float bia = bo[n];
                #pragma unroll
                for (int r = 0; r < 4; ++r)
                    outf[(size_t)(row + r) * 1024 + n] = acc[mi][nj][r] + bia;
            }
        }
    }
}

// ---------------------------------------------------------------------------
// Flash attention: fixed-base softmax (scores bounded => no max tracking),
// wave-private P (no barrier), 32 q/wave, VGPR prefetch of next K/V tile,
// ping-pong K/V LDS (one barrier per tile), exp2 softmax, setprio on MFMA.
// Mask: p = mq ? (mk ? exp(s) : 0) : 1 — exactly matches reference semantics.
// ---------------------------------------------------------------------------
__global__ __launch_bounds__(256) void attn(
    const __bf16* __restrict__ qb, const __bf16* __restrict__ kb,
    const __bf16* __restrict__ vb, const int* __restrict__ mask,
    __bf16* __restrict__ ctx)
{
    const int bh = blockIdx.x;
    const int q0 = blockIdx.y * 128;
    const int b  = bh >> 4;
    const int h  = bh & 15;
    const size_t base = (size_t)bh * Ss * Kk;

    __shared__ __align__(16) __bf16 Qs[128][72];
    __shared__ __align__(16) __bf16 Ks[2][64][72];
    __shared__ __align__(16) __bf16 VTs[2][64][72];
    __shared__ __align__(16) __bf16 Ps[4][32][72];
    __shared__ float mkf[1024];

    const int t    = threadIdx.x;
    const int wave = t >> 6, lane = t & 63;
    const int quad = lane >> 4, l16 = lane & 15;
    const int qbase = wave * 32;

    #pragma unroll
    for (int p = 0; p < 4; ++p) {
        int idx = t + p * 256;
        int r = idx >> 3, g = idx & 7;
        *(bf16x8*)&Qs[r][g * 8] =
            *(const bf16x8*)(qb + base + (size_t)(q0 + r) * Kk + g * 8);
    }
    {
        int4 mi = *(const int4*)(mask + b * Ss + t * 4);
        mkf[t * 4 + 0] = (float)mi.x;
        mkf[t * 4 + 1] = (float)mi.y;
        mkf[t * 4 + 2] = (float)mi.z;
        mkf[t * 4 + 3] = (float)mi.w;
    }

    const int r0 = t >> 3, c0 = (t & 7) * 8;
    bf16x8 kr0, kr1, vr0, vr1;
    kr0 = *(const bf16x8*)(kb + base + (size_t)(r0) * Kk + c0);
    kr1 = *(const bf16x8*)(kb + base + (size_t)(r0 + 32) * Kk + c0);
    vr0 = *(const bf16x8*)(vb + base + (size_t)(r0) * Ss + c0);
    vr1 = *(const bf16x8*)(vb + base + (size_t)(r0 + 32) * Ss + c0);

    __syncthreads();   // Qs + mkf visible

    bf16x8 aq[2][2];
    #pragma unroll
    for (int rg = 0; rg < 2; ++rg) {
        aq[rg][0] = *(const bf16x8*)&Qs[qbase + rg * 16 + l16][quad * 8];
        aq[rg][1] = *(const bf16x8*)&Qs[qbase + rg * 16 + l16][32 + quad * 8];
    }
    float mqf[2][4], omqf[2][4];
    #pragma unroll
    for (int rg = 0; rg < 2; ++rg)
        #pragma unroll
        for (int i = 0; i < 4; ++i) {
            float m = mkf[q0 + qbase + rg * 16 + quad * 4 + i];
            mqf[rg][i] = m; omqf[rg][i] = 1.0f - m;
        }

    f32x4 O[2][4];
    float lsum[2][4];
    #pragma unroll
    for (int rg = 0; rg < 2; ++rg)
        #pragma unroll
        for (int nb = 0; nb < 4; ++nb) O[rg][nb] = (f32x4){0.f, 0.f, 0.f, 0.f};
    #pragma unroll
    for (int rg = 0; rg < 2; ++rg)
        #pragma unroll
        for (int i = 0; i < 4; ++i) lsum[rg][i] = 0.f;

    for (int kt = 0; kt < Ss; kt += 64) {
        const int p = (kt >> 6) & 1;
        *(bf16x8*)&Ks[p][r0][c0] = kr0;
        *(bf16x8*)&Ks[p][r0 + 32][c0] = kr1;
        *(bf16x8*)&VTs[p][r0][c0] = vr0;
        *(bf16x8*)&VTs[p][r0 + 32][c0] = vr1;
        __syncthreads();   // the ONLY barrier per tile

        int ktn = kt + 64;
        if (ktn < Ss) {    // issue next tile's loads; in flight across compute
            kr0 = *(const bf16x8*)(kb + base + (size_t)(ktn + r0) * Kk + c0);
            kr1 = *(const bf16x8*)(kb + base + (size_t)(ktn + r0 + 32) * Kk + c0);
            vr0 = *(const bf16x8*)(vb + base + (size_t)(r0) * Ss + ktn + c0);
            vr1 = *(const bf16x8*)(vb + base + (size_t)(r0 + 32) * Ss + ktn + c0);
        }

        float mkv[4];
        #pragma unroll
        for (int nb = 0; nb < 4; ++nb) mkv[nb] = mkf[kt + nb * 16 + l16];

        bf16x8 kb0[4], kb1[4];
        #pragma unroll
        for (int nb = 0; nb < 4; ++nb) {
            kb0[nb] = *(const bf16x8*)&Ks[p][nb * 16 + l16][quad * 8];
            kb1[nb] = *(const bf16x8*)&Ks[p][nb * 16 + l16][32 + quad * 8];
        }

        f32x4 s[2][4];
        __builtin_amdgcn_s_setprio(1);
        #pragma unroll
        for (int rg = 0; rg < 2; ++rg)
            #pragma unroll
            for (int nb = 0; nb < 4; ++nb) {
                f32x4 a = (f32x4){0.f, 0.f, 0.f, 0.f};
                a = MFMA16(aq[rg][0], kb0[nb], a);
                a = MFMA16(aq[rg][1], kb1[nb], a);
                s[rg][nb] = a;
            }
        __builtin_amdgcn_s_setprio(0);

        #pragma unroll
        for (int rg = 0; rg < 2; ++rg)
            #pragma unroll
            for (int i = 0; i < 4; ++i) {
                float ls = 0.f;
                #pragma unroll
                for (int nb = 0; nb < 4; ++nb) {
                    float pv = exp2_hw(s[rg][nb][i]) * mkv[nb];
                    pv = pv * mqf[rg][i] + omqf[rg][i];
                    Ps[wave][rg * 16 + quad * 4 + i][nb * 16 + l16] = (__bf16)pv;
                    ls += pv;
                }
                lsum[rg][i] += ls;
            }

        bf16x8 ap0[2], ap1[2];
        #pragma unroll
        for (int rg = 0; rg < 2; ++rg) {
            ap0[rg] = *(const bf16x8*)&Ps[wave][rg * 16 + l16][quad * 8];
            ap1[rg] = *(const bf16x8*)&Ps[wave][rg * 16 + l16][32 + quad * 8];
        }
        __builtin_amdgcn_s_setprio(1);
        #pragma unroll
        for (int nb = 0; nb < 4; ++nb) {
            bf16x8 vb0 = *(const bf16x8*)&VTs[p][nb * 16 + l16][quad * 8];
            bf16x8 vb1 = *(const bf16x8*)&VTs[p][nb * 16 + l16][32 + quad * 8];
            #pragma unroll
            for (int rg = 0; rg < 2; ++rg) {
                O[rg][nb] = MFMA16(ap0[rg], vb0, O[rg][nb]);
                O[rg][nb] = MFMA16(ap1[rg], vb1, O[rg][nb]);
            }
        }
        __builtin_amdgcn_s_setprio(0);
    }

    #pragma unroll
    for (int rg = 0; rg < 2; ++rg)
        #pragma unroll
        for (int i = 0; i < 4; ++i) {
            float l = lsum[rg][i];
            l += __shfl_xor(l, 1);
            l += __shfl_xor(l, 2);
            l += __shfl_xor(l, 4);
            l += __shfl_xor(l, 8);
            float inv = 1.0f / l;
            int srow = q0 + qbase + rg * 16 + quad * 4 + i;
            __bf16* dst = ctx + ((size_t)(b * Ss + srow) * Hh + h) * Kk;
            #pragma unroll
            for (int nb = 0; nb < 4; ++nb)
                dst[nb * 16 + l16] = (__bf16)(O[rg][nb][i] * inv);
        }
}

extern "C" void kernel_launch(void* const* d_in, const int* in_sizes, int n_in,
                              void* d_out, int out_size, void* d_ws, size_t ws_size,
                              hipStream_t stream) {
    const float* x    = (const float*)d_in[0];
    const int*   mask = (const int*)d_in[1];
    const float* Wq   = (const float*)d_in[2];
    const float* bq   = (const float*)d_in[3];
    const float* Wk   = (const float*)d_in[4];
    const float* bk   = (const float*)d_in[5];
    const float* Wv   = (const float*)d_in[6];
    const float* bv   = (const float*)d_in[7];
    const float* Wo   = (const float*)d_in[8];
    const float* bo   = (const float*)d_in[9];

    __bf16* xb   = (__bf16*)d_ws;
    __bf16* WT   = xb + XB_E;
    __bf16* WoT  = WT + WT_E;
    __bf16* qb   = WoT + WOT_E;
    __bf16* kb   = qb + QKV_E;
    __bf16* vb   = kb + QKV_E;
    __bf16* ctxb = vb + QKV_E;
    float* out = (float*)d_out;

    prep<<<dim3(16, 16, 5), 256, 0, stream>>>(x, Wq, Wk, Wv, Wo, xb, WT, WoT);
    gemm_bt<384><<<dim3(8, 32), 512, 0, stream>>>(xb, WT, 0, qb, kb, vb,
                                                  bq, bk, bv, nullptr, nullptr);
    attn<<<dim3(128, 8), 256, 0, stream>>>(qb, kb, vb, mask, ctxb);
    gemm_bt<128><<<dim3(8, 32), 512, 0, stream>>>(ctxb, WoT, 1, nullptr, nullptr,
                                                  nullptr, nullptr, nullptr,
                                                  nullptr, out, bo);
}

// Round 7
// 263.012 us; speedup vs baseline: 1.0135x; 1.0135x over previous
//
#include <hip/hip_runtime.h>
#include <math.h>

#define Ss 1024
#define Dd 1024
#define Hh 16
#define Kk 64

typedef __bf16 bf16x8 __attribute__((ext_vector_type(8)));
typedef __bf16 bf16x4 __attribute__((ext_vector_type(4)));
typedef float  f32x4  __attribute__((ext_vector_type(4)));

#define MFMA16(a, b, c) __builtin_amdgcn_mfma_f32_16x16x32_bf16(a, b, c, 0, 0, 0)

// ws element offsets (bf16 units)
#define XB_E   8388608u
#define WT_E   3145728u
#define WOT_E  1048576u
#define QKV_E  8388608u

// Q scale: (1/8) * log2(e) so attn can use raw v_exp_f32 (2^x).
#define QSC 0.18033688011112042f

// v_exp_f32 is natively 2^x; log2(e) is folded into the Q scale in gemm.
__device__ __forceinline__ float exp2_hw(float x) {
    float r; asm("v_exp_f32 %0, %1" : "=v"(r) : "v"(x)); return r;
}

// global -> LDS DMA, 16B per lane. LDS dest: wave-uniform base + lane*16.
typedef __attribute__((address_space(1))) const void gas_void;
typedef __attribute__((address_space(3))) void las_void;
__device__ __forceinline__ void gll16(const __bf16* g, char* l) {
    __builtin_amdgcn_global_load_lds((gas_void*)g, (las_void*)l, 16, 0, 0);
}

// ---------------------------------------------------------------------------
// prep: z<4 -> transpose+cast weight matrix z; z==4 -> cast x to bf16
// ---------------------------------------------------------------------------
__global__ __launch_bounds__(256) void prep(
    const float* __restrict__ x,
    const float* __restrict__ Wq, const float* __restrict__ Wk,
    const float* __restrict__ Wv, const float* __restrict__ Wo,
    __bf16* __restrict__ xb, __bf16* __restrict__ WT, __bf16* __restrict__ WoT)
{
    __shared__ float tile[64][65];
    const int z = blockIdx.z;
    const int t = threadIdx.x;

    if (z == 4) {   // x cast: 256 blocks, 32 rows x 1024 cols each
        size_t blk = blockIdx.y * 16 + blockIdx.x;
        const float4* src = (const float4*)(x + blk * 32768);
        bf16x4* dst = (bf16x4*)(((__bf16*)xb) + blk * 32768);
        #pragma unroll
        for (int u = 0; u < 32; ++u) {
            float4 v = src[u * 256 + t];
            dst[u * 256 + t] =
                (bf16x4){(__bf16)v.x, (__bf16)v.y, (__bf16)v.z, (__bf16)v.w};
        }
        return;
    }

    const float* src = (z == 0) ? Wq : (z == 1) ? Wk : (z == 2) ? Wv : Wo;
    __bf16* dst = (z < 3) ? (WT + (size_t)z * 1048576) : WoT;

    int r0 = blockIdx.y * 64, c0 = blockIdx.x * 64;
    int rr = t >> 2, cg = (t & 3) * 16;

    #pragma unroll
    for (int u = 0; u < 4; ++u) {
        float4 v = *(const float4*)(src + (size_t)(r0 + rr) * 1024 + c0 + cg + u * 4);
        tile[rr][cg + u * 4 + 0] = v.x;
        tile[rr][cg + u * 4 + 1] = v.y;
        tile[rr][cg + u * 4 + 2] = v.z;
        tile[rr][cg + u * 4 + 3] = v.w;
    }
    __syncthreads();
    bf16x8 o0, o1;
    #pragma unroll
    for (int jj = 0; jj < 8; ++jj) o0[jj] = (__bf16)tile[cg + jj][rr];
    #pragma unroll
    for (int jj = 0; jj < 8; ++jj) o1[jj] = (__bf16)tile[cg + 8 + jj][rr];
    __bf16* dp = dst + (size_t)(c0 + rr) * 1024 + r0 + cg;
    *(bf16x8*)dp = o0;
    *(bf16x8*)(dp + 8) = o1;
}

// ---------------------------------------------------------------------------
// bf16 MFMA GEMM, C = A(MxK) * Bt(NxK)^T.  m201-style FINE-GRAINED PHASES.
// All coarse schedules measured 75-85us (MfmaUtil pinned ~25% = m233's
// 2-phase ceiling: stage+vmcnt+barrier serialization). This version ports the
// proven rhythm: per K-tile, 4 phases (BN=256) of
//   { ds_read subtile | stage 2-4 glls | barrier | lgkmcnt(0) | 16 MFMA | barrier }
// with counted vmcnt placed ONE PHASE AHEAD of use:
//   issue order/tile: [a0,a2,b0,b1](ph0) [b2,b3](ph1) [a1,a3](ph2)
//   ph1 top: vmcnt(4)  -> retires this tile's late A (read at ph2)
//   ph3 top: vmcnt(2)  -> retires next tile's early 6 (read at ph0),
//                         leaving 2 in flight across the boundary.
// Cross-wave safety: every wait at phase p precedes phase p's barriers, and
// the dependent reads occur after them -> all waves' glls retired.
// BN=128 (out-gemm): 2-phase analog, vmcnt(0) at both phase tops.
// Geometry: BM=BN=256 (R5-best), 8 waves 2Mx4N, 128x64/wave, acc[8][4].
// T2 XOR swizzle (conflicts measured 0), T1 XCD swizzle, T5 setprio.
// mode 0: QKV epilogue (Q pre-scaled by log2e/8); mode 1: fp32 out + bias.
// ---------------------------------------------------------------------------
template <int BN>
__global__ __launch_bounds__(512) void gemm_bt(
    const __bf16* __restrict__ A, const __bf16* __restrict__ Bt, int mode,
    __bf16* __restrict__ qb, __bf16* __restrict__ kb, __bf16* __restrict__ vb,
    const float* __restrict__ bq, const float* __restrict__ bk,
    const float* __restrict__ bv,
    float* __restrict__ outf, const float* __restrict__ bo)
{
    constexpr int NB = BN / 64;      // B gll chunks (4 or 2)
    constexpr int NJ = BN / 64;      // acc columns per wave (4 or 2)
    constexpr int WN = BN / 4;       // per-wave N span

    __shared__ __align__(16) __bf16 As[2][256][64];
    __shared__ __align__(16) __bf16 Bs[2][BN][64];

    const int t = threadIdx.x;
    const int wave = t >> 6, lane = t & 63;
    const int quad = lane >> 4, l16 = lane & 15;
    const int wm = wave >> 2, wn = wave & 3;          // 2M x 4N waves

    // Bijective XCD swizzle (nwg % 8 == 0 for both grids).
    const int nwg = gridDim.x * gridDim.y;
    const int cpx = nwg >> 3;
    int g = blockIdx.y * gridDim.x + blockIdx.x;
    g = (g & 7) * cpx + (g >> 3);
    const int bx = g % gridDim.x, by = g / gridDim.x;
    const int m0 = by * 256, n0 = bx * BN;

    // Staging: thread t -> row (chunk*64 + t>>3), 16B piece (t&7). Global col
    // pre-swizzled so linear LDS (row, cb) holds global (row, cb^((row&7)<<4)).
    const int srow = t >> 3;
    const int scol = (((t & 7) ^ (srow & 7)) * 8);
    const __bf16* pa = A  + (size_t)(m0 + srow) * 1024 + scol;
    const __bf16* pb = Bt + (size_t)(n0 + srow) * 1024 + scol;
    char* lA = (char*)(&As[0][0][0]) + t * 16;
    char* lB = (char*)(&Bs[0][0][0]) + t * 16;

#define SGA(slot, k0, c) gll16(pa + (k0) + (c) * 65536, lA + (slot) * 32768 + (c) * 8192)
#define SGB(slot, k0, c) gll16(pb + (k0) + (c) * 65536, lB + (slot) * (BN * 128) + (c) * 8192)

    // Prologue: tile 0 -> slot 0, issue order E then L.
    SGA(0, 0, 0); SGA(0, 0, 2);
    #pragma unroll
    for (int c = 0; c < NB; ++c) SGB(0, 0, c);
    SGA(0, 0, 1); SGA(0, 0, 3);

    f32x4 acc[8][NJ];
    #pragma unroll
    for (int i = 0; i < 8; ++i)
        #pragma unroll
        for (int j = 0; j < NJ; ++j) acc[i][j] = (f32x4){0.f, 0.f, 0.f, 0.f};

    const int swz = (l16 & 7) << 4;   // read-side XOR (row&7 == l16&7)

    asm volatile("s_waitcnt vmcnt(2)" ::: "memory");   // retire E_0
    __syncthreads();

    for (int it = 0; it < 16; ++it) {
        const int s = it & 1, ns = s ^ 1;
        const int kn = (it + 1) * 64;
        const bool st = (it < 15);
        const char* baseA = (const char*)&As[s][0][0];
        const char* baseB = (const char*)&Bs[s][0][0];

        bf16x8 af[4][2], b0f[2][2], b1f[2][2];

        if constexpr (BN == 256) {
            // ---- ph0: read A-mh0 + B-nh0; stage a0,a2,b0,b1 ----
            #pragma unroll
            for (int mi = 0; mi < 4; ++mi) {
                int ra = (wm * 128 + mi * 16 + l16) * 128;
                af[mi][0] = *(const bf16x8*)(baseA + ra + ((quad * 16) ^ swz));
                af[mi][1] = *(const bf16x8*)(baseA + ra + ((64 + quad * 16) ^ swz));
            }
            #pragma unroll
            for (int nj = 0; nj < 2; ++nj) {
                int rb = (wn * 64 + nj * 16 + l16) * 128;
                b0f[nj][0] = *(const bf16x8*)(baseB + rb + ((quad * 16) ^ swz));
                b0f[nj][1] = *(const bf16x8*)(baseB + rb + ((64 + quad * 16) ^ swz));
            }
            if (st) { SGA(ns, kn, 0); SGA(ns, kn, 2); SGB(ns, kn, 0); SGB(ns, kn, 1); }
            __builtin_amdgcn_s_barrier();
            asm volatile("s_waitcnt lgkmcnt(0)" ::: "memory");
            __builtin_amdgcn_sched_barrier(0);
            __builtin_amdgcn_s_setprio(1);
            #pragma unroll
            for (int mi = 0; mi < 4; ++mi)
                #pragma unroll
                for (int nj = 0; nj < 2; ++nj)
                    acc[mi][nj] = MFMA16(af[mi][1], b0f[nj][1],
                                  MFMA16(af[mi][0], b0f[nj][0], acc[mi][nj]));
            __builtin_amdgcn_s_setprio(0);
            __builtin_amdgcn_s_barrier();

            // ---- ph1: retire late A of THIS tile; read B-nh1; stage b2,b3 ----
            if (it == 15) asm volatile("s_waitcnt vmcnt(0)" ::: "memory");
            else          asm volatile("s_waitcnt vmcnt(4)" ::: "memory");
            #pragma unroll
            for (int nj = 0; nj < 2; ++nj) {
                int rb = (wn * 64 + (2 + nj) * 16 + l16) * 128;
                b1f[nj][0] = *(const bf16x8*)(baseB + rb + ((quad * 16) ^ swz));
                b1f[nj][1] = *(const bf16x8*)(baseB + rb + ((64 + quad * 16) ^ swz));
            }
            if (st) { SGB(ns, kn, 2); SGB(ns, kn, 3); }
            __builtin_amdgcn_s_barrier();
            asm volatile("s_waitcnt lgkmcnt(0)" ::: "memory");
            __builtin_amdgcn_sched_barrier(0);
            __builtin_amdgcn_s_setprio(1);
            #pragma unroll
            for (int mi = 0; mi < 4; ++mi)
                #pragma unroll
                for (int nj = 0; nj < 2; ++nj)
                    acc[mi][2 + nj] = MFMA16(af[mi][1], b1f[nj][1],
                                      MFMA16(af[mi][0], b1f[nj][0], acc[mi][2 + nj]));
            __builtin_amdgcn_s_setprio(0);
            __builtin_amdgcn_s_barrier();

            // ---- ph2: read A-mh1 (retired @ph1); stage a1,a3 ----
            #pragma unroll
            for (int mi = 0; mi < 4; ++mi) {
                int ra = (wm * 128 + (4 + mi) * 16 + l16) * 128;
                af[mi][0] = *(const bf16x8*)(baseA + ra + ((quad * 16) ^ swz));
                af[mi][1] = *(const bf16x8*)(baseA + ra + ((64 + quad * 16) ^ swz));
            }
            if (st) { SGA(ns, kn, 1); SGA(ns, kn, 3); }
            __builtin_amdgcn_s_barrier();
            asm volatile("s_waitcnt lgkmcnt(0)" ::: "memory");
            __builtin_amdgcn_sched_barrier(0);
            __builtin_amdgcn_s_setprio(1);
            #pragma unroll
            for (int mi = 0; mi < 4; ++mi)
                #pragma unroll
                for (int nj = 0; nj < 2; ++nj)
                    acc[4 + mi][nj] = MFMA16(af[mi][1], b0f[nj][1],
                                      MFMA16(af[mi][0], b0f[nj][0], acc[4 + mi][nj]));
            __builtin_amdgcn_s_setprio(0);
            __builtin_amdgcn_s_barrier();

            // ---- ph3: retire NEXT tile's early 6 (2 stay in flight) ----
            asm volatile("s_waitcnt vmcnt(2)" ::: "memory");
            __builtin_amdgcn_s_barrier();
            __builtin_amdgcn_s_setprio(1);
            #pragma unroll
            for (int mi = 0; mi < 4; ++mi)
                #pragma unroll
                for (int nj = 0; nj < 2; ++nj)
                    acc[4 + mi][2 + nj] = MFMA16(af[mi][1], b1f[nj][1],
                                          MFMA16(af[mi][0], b1f[nj][0], acc[4 + mi][2 + nj]));
            __builtin_amdgcn_s_setprio(0);
            __builtin_amdgcn_s_barrier();
        } else {
            // BN==128: 2 phases; vmcnt(0) at both tops (cross-wave-safe).
            // ---- ph0: retire L_it; read A-mh0 + B(all); stage E'(4) ----
            asm volatile("s_waitcnt vmcnt(0)" ::: "memory");
            #pragma unroll
            for (int mi = 0; mi < 4; ++mi) {
                int ra = (wm * 128 + mi * 16 + l16) * 128;
                af[mi][0] = *(const bf16x8*)(baseA + ra + ((quad * 16) ^ swz));
                af[mi][1] = *(const bf16x8*)(baseA + ra + ((64 + quad * 16) ^ swz));
            }
            #pragma unroll
            for (int nj = 0; nj < 2; ++nj) {
                int rb = (wn * 32 + nj * 16 + l16) * 128;
                b0f[nj][0] = *(const bf16x8*)(baseB + rb + ((quad * 16) ^ swz));
                b0f[nj][1] = *(const bf16x8*)(baseB + rb + ((64 + quad * 16) ^ swz));
            }
            if (st) { SGA(ns, kn, 0); SGA(ns, kn, 2); SGB(ns, kn, 0); SGB(ns, kn, 1); }
            __builtin_amdgcn_s_barrier();
            asm volatile("s_waitcnt lgkmcnt(0)" ::: "memory");
            __builtin_amdgcn_sched_barrier(0);
            __builtin_amdgcn_s_setprio(1);
            #pragma unroll
            for (int mi = 0; mi < 4; ++mi)
                #pragma unroll
                for (int nj = 0; nj < 2; ++nj)
                    acc[mi][nj] = MFMA16(af[mi][1], b0f[nj][1],
                                  MFMA16(af[mi][0], b0f[nj][0], acc[mi][nj]));
            __builtin_amdgcn_s_setprio(0);
            __builtin_amdgcn_s_barrier();

            // ---- ph1: retire E_{it+1}; read A-mh1; stage L'(2) ----
            asm volatile("s_waitcnt vmcnt(0)" ::: "memory");
            #pragma unroll
            for (int mi = 0; mi < 4; ++mi) {
                int ra = (wm * 128 + (4 + mi) * 16 + l16) * 128;
                af[mi][0] = *(const bf16x8*)(baseA + ra + ((quad * 16) ^ swz));
                af[mi][1] = *(const bf16x8*)(baseA + ra + ((64 + quad * 16) ^ swz));
            }
            if (st) { SGA(ns, kn, 1); SGA(ns, kn, 3); }
            __builtin_amdgcn_s_barrier();
            asm volatile("s_waitcnt lgkmcnt(0)" ::: "memory");
            __builtin_amdgcn_sched_barrier(0);
            __builtin_amdgcn_s_setprio(1);
            #pragma unroll
            for (int mi = 0; mi < 4; ++mi)
                #pragma unroll
                for (int nj = 0; nj < 2; ++nj)
                    acc[4 + mi][nj] = MFMA16(af[mi][1], b0f[nj][1],
                                      MFMA16(af[mi][0], b0f[nj][0], acc[4 + mi][nj]));
            __builtin_amdgcn_s_setprio(0);
            __builtin_amdgcn_s_barrier();
        }
    }
#undef SGA
#undef SGB

    if (mode == 0) {
        #pragma unroll
        for (int mi = 0; mi < 8; ++mi) {
            int row = m0 + wm * 128 + mi * 16 + quad * 4;
            int b = row >> 10, sx = row & 1023;
            #pragma unroll
            for (int nj = 0; nj < NJ; ++nj) {
                int c16 = n0 + wn * WN + nj * 16;
                int z = c16 >> 10;
                int n1 = (c16 + l16) & 1023;
                int h = n1 >> 6, ch = n1 & 63;
                if (z == 0) {
                    float bia = bq[n1];
                    __bf16* dst = qb + ((size_t)(b * Hh + h) * Ss + sx) * Kk + ch;
                    #pragma unroll
                    for (int r = 0; r < 4; ++r)
                        dst[(size_t)r * Kk] = (__bf16)((acc[mi][nj][r] + bia) * QSC);
                } else if (z == 1) {
                    float bia = bk[n1];
                    __bf16* dst = kb + ((size_t)(b * Hh + h) * Ss + sx) * Kk + ch;
                    #pragma unroll
                    for (int r = 0; r < 4; ++r)
                        dst[(size_t)r * Kk] = (__bf16)(acc[mi][nj][r] + bia);
                } else {
                    float bia = bv[n1];
                    bf16x4 o;
                    #pragma unroll
                    for (int r = 0; r < 4; ++r) o[r] = (__bf16)(acc[mi][nj][r] + bia);
                    *(bf16x4*)(vb + ((size_t)(b * Hh + h) * Kk + ch) * Ss + sx) = o;
                }
            }
        }
    } else {
        #pragma unroll
        for (int mi = 0; mi < 8; ++mi) {
            int row = m0 + wm * 128 + mi * 16 + quad * 4;
            #pragma unroll
            for (int nj = 0; nj < NJ; ++nj) {
                int n = n0 + wn * WN + nj * 16 + l16;
                float bia = bo[n];
                #pragma unroll
                for (int r = 0; r < 4; ++r)
                    outf[(size_t)(row + r) * 1024 + n] = acc[mi][nj][r] + bia;
            }
        }
    }
}

// ---------------------------------------------------------------------------
// Flash attention: fixed-base softmax (scores bounded => no max tracking),
// wave-private P (no barrier), 32 q/wave, VGPR prefetch of next K/V tile,
// ping-pong K/V LDS (one barrier per tile), exp2 softmax, setprio on MFMA.
// Mask: p = mq ? (mk ? exp(s) : 0) : 1 — exactly matches reference semantics.
// ---------------------------------------------------------------------------
__global__ __launch_bounds__(256) void attn(
    const __bf16* __restrict__ qb, const __bf16* __restrict__ kb,
    const __bf16* __restrict__ vb, const int* __restrict__ mask,
    __bf16* __restrict__ ctx)
{
    const int bh = blockIdx.x;
    const int q0 = blockIdx.y * 128;
    const int b  = bh >> 4;
    const int h  = bh & 15;
    const size_t base = (size_t)bh * Ss * Kk;

    __shared__ __align__(16) __bf16 Qs[128][72];
    __shared__ __align__(16) __bf16 Ks[2][64][72];
    __shared__ __align__(16) __bf16 VTs[2][64][72];
    __shared__ __align__(16) __bf16 Ps[4][32][72];
    __shared__ float mkf[1024];

    const int t    = threadIdx.x;
    const int wave = t >> 6, lane = t & 63;
    const int quad = lane >> 4, l16 = lane & 15;
    const int qbase = wave * 32;

    #pragma unroll
    for (int p = 0; p < 4; ++p) {
        int idx = t + p * 256;
        int r = idx >> 3, g = idx & 7;
        *(bf16x8*)&Qs[r][g * 8] =
            *(const bf16x8*)(qb + base + (size_t)(q0 + r) * Kk + g * 8);
    }
    {
        int4 mi = *(const int4*)(mask + b * Ss + t * 4);
        mkf[t * 4 + 0] = (float)mi.x;
        mkf[t * 4 + 1] = (float)mi.y;
        mkf[t * 4 + 2] = (float)mi.z;
        mkf[t * 4 + 3] = (float)mi.w;
    }

    const int r0 = t >> 3, c0 = (t & 7) * 8;
    bf16x8 kr0, kr1, vr0, vr1;
    kr0 = *(const bf16x8*)(kb + base + (size_t)(r0) * Kk + c0);
    kr1 = *(const bf16x8*)(kb + base + (size_t)(r0 + 32) * Kk + c0);
    vr0 = *(const bf16x8*)(vb + base + (size_t)(r0) * Ss + c0);
    vr1 = *(const bf16x8*)(vb + base + (size_t)(r0 + 32) * Ss + c0);

    __syncthreads();   // Qs + mkf visible

    bf16x8 aq[2][2];
    #pragma unroll
    for (int rg = 0; rg < 2; ++rg) {
        aq[rg][0] = *(const bf16x8*)&Qs[qbase + rg * 16 + l16][quad * 8];
        aq[rg][1] = *(const bf16x8*)&Qs[qbase + rg * 16 + l16][32 + quad * 8];
    }
    float mqf[2][4], omqf[2][4];
    #pragma unroll
    for (int rg = 0; rg < 2; ++rg)
        #pragma unroll
        for (int i = 0; i < 4; ++i) {
            float m = mkf[q0 + qbase + rg * 16 + quad * 4 + i];
            mqf[rg][i] = m; omqf[rg][i] = 1.0f - m;
        }

    f32x4 O[2][4];
    float lsum[2][4];
    #pragma unroll
    for (int rg = 0; rg < 2; ++rg)
        #pragma unroll
        for (int nb = 0; nb < 4; ++nb) O[rg][nb] = (f32x4){0.f, 0.f, 0.f, 0.f};
    #pragma unroll
    for (int rg = 0; rg < 2; ++rg)
        #pragma unroll
        for (int i = 0; i < 4; ++i) lsum[rg][i] = 0.f;

    for (int kt = 0; kt < Ss; kt += 64) {
        const int p = (kt >> 6) & 1;
        *(bf16x8*)&Ks[p][r0][c0] = kr0;
        *(bf16x8*)&Ks[p][r0 + 32][c0] = kr1;
        *(bf16x8*)&VTs[p][r0][c0] = vr0;
        *(bf16x8*)&VTs[p][r0 + 32][c0] = vr1;
        __syncthreads();   // the ONLY barrier per tile

        int ktn = kt + 64;
        if (ktn < Ss) {    // issue next tile's loads; in flight across compute
            kr0 = *(const bf16x8*)(kb + base + (size_t)(ktn + r0) * Kk + c0);
            kr1 = *(const bf16x8*)(kb + base + (size_t)(ktn + r0 + 32) * Kk + c0);
            vr0 = *(const bf16x8*)(vb + base + (size_t)(r0) * Ss + ktn + c0);
            vr1 = *(const bf16x8*)(vb + base + (size_t)(r0 + 32) * Ss + ktn + c0);
        }

        float mkv[4];
        #pragma unroll
        for (int nb = 0; nb < 4; ++nb) mkv[nb] = mkf[kt + nb * 16 + l16];

        bf16x8 kb0[4], kb1[4];
        #pragma unroll
        for (int nb = 0; nb < 4; ++nb) {
            kb0[nb] = *(const bf16x8*)&Ks[p][nb * 16 + l16][quad * 8];
            kb1[nb] = *(const bf16x8*)&Ks[p][nb * 16 + l16][32 + quad * 8];
        }

        f32x4 s[2][4];
        __builtin_amdgcn_s_setprio(1);
        #pragma unroll
        for (int rg = 0; rg < 2; ++rg)
            #pragma unroll
            for (int nb = 0; nb < 4; ++nb) {
                f32x4 a = (f32x4){0.f, 0.f, 0.f, 0.f};
                a = MFMA16(aq[rg][0], kb0[nb], a);
                a = MFMA16(aq[rg][1], kb1[nb], a);
                s[rg][nb] = a;
            }
        __builtin_amdgcn_s_setprio(0);

        #pragma unroll
        for (int rg = 0; rg < 2; ++rg)
            #pragma unroll
            for (int i = 0; i < 4; ++i) {
                float ls = 0.f;
                #pragma unroll
                for (int nb = 0; nb < 4; ++nb) {
                    float pv = exp2_hw(s[rg][nb][i]) * mkv[nb];
                    pv = pv * mqf[rg][i] + omqf[rg][i];
                    Ps[wave][rg * 16 + quad * 4 + i][nb * 16 + l16] = (__bf16)pv;
                    ls += pv;
                }
                lsum[rg][i] += ls;
            }

        bf16x8 ap0[2], ap1[2];
        #pragma unroll
        for (int rg = 0; rg < 2; ++rg) {
            ap0[rg] = *(const bf16x8*)&Ps[wave][rg * 16 + l16][quad * 8];
            ap1[rg] = *(const bf16x8*)&Ps[wave][rg * 16 + l16][32 + quad * 8];
        }
        __builtin_amdgcn_s_setprio(1);
        #pragma unroll
        for (int nb = 0; nb < 4; ++nb) {
            bf16x8 vb0 = *(const bf16x8*)&VTs[p][nb * 16 + l16][quad * 8];
            bf16x8 vb1 = *(const bf16x8*)&VTs[p][nb * 16 + l16][32 + quad * 8];
            #pragma unroll
            for (int rg = 0; rg < 2; ++rg) {
                O[rg][nb] = MFMA16(ap0[rg], vb0, O[rg][nb]);
                O[rg][nb] = MFMA16(ap1[rg], vb1, O[rg][nb]);
            }
        }
        __builtin_amdgcn_s_setprio(0);
    }

    #pragma unroll
    for (int rg = 0; rg < 2; ++rg)
        #pragma unroll
        for (int i = 0; i < 4; ++i) {
            float l = lsum[rg][i];
            l += __shfl_xor(l, 1);
            l += __shfl_xor(l, 2);
            l += __shfl_xor(l, 4);
            l += __shfl_xor(l, 8);
            float inv = 1.0f / l;
            int srow = q0 + qbase + rg * 16 + quad * 4 + i;
            __bf16* dst = ctx + ((size_t)(b * Ss + srow) * Hh + h) * Kk;
            #pragma unroll
            for (int nb = 0; nb < 4; ++nb)
                dst[nb * 16 + l16] = (__bf16)(O[rg][nb][i] * inv);
        }
}

extern "C" void kernel_launch(void* const* d_in, const int* in_sizes, int n_in,
                              void* d_out, int out_size, void* d_ws, size_t ws_size,
                              hipStream_t stream) {
    const float* x    = (const float*)d_in[0];
    const int*   mask = (const int*)d_in[1];
    const float* Wq   = (const float*)d_in[2];
    const float* bq   = (const float*)d_in[3];
    const float* Wk   = (const float*)d_in[4];
    const float* bk   = (const float*)d_in[5];
    const float* Wv   = (const float*)d_in[6];
    const float* bv   = (const float*)d_in[7];
    const float* Wo   = (const float*)d_in[8];
    const float* bo   = (const float*)d_in[9];

    __bf16* xb   = (__bf16*)d_ws;
    __bf16* WT   = xb + XB_E;
    __bf16* WoT  = WT + WT_E;
    __bf16* qb   = WoT + WOT_E;
    __bf16* kb   = qb + QKV_E;
    __bf16* vb   = kb + QKV_E;
    __bf16* ctxb = vb + QKV_E;
    float* out = (float*)d_out;

    prep<<<dim3(16, 16, 5), 256, 0, stream>>>(x, Wq, Wk, Wv, Wo, xb, WT, WoT);
    gemm_bt<256><<<dim3(12, 32), 512, 0, stream>>>(xb, WT, 0, qb, kb, vb,
                                                   bq, bk, bv, nullptr, nullptr);
    attn<<<dim3(128, 8), 256, 0, stream>>>(qb, kb, vb, mask, ctxb);
    gemm_bt<128><<<dim3(8, 32), 512, 0, stream>>>(ctxb, WoT, 1, nullptr, nullptr,
                                                  nullptr, nullptr, nullptr,
                                                  nullptr, out, bo);
}